// Round 7
// baseline (241.168 us; speedup 1.0000x reference)
//
#include <hip/hip_runtime.h>
#include <hip/hip_bf16.h>
#include <stdint.h>

#define BATCH 2
#define LQ 2048
#define LK 2048
#define DIM 1024
#define HEADS 8
#define DH 64
#define INNER 512  // HEADS*DH

typedef __attribute__((ext_vector_type(8))) short short8;
typedef __attribute__((ext_vector_type(4))) float f32x4;

__device__ __forceinline__ float bf2f(unsigned short u) {
    union { unsigned int i; float f; } v;
    v.i = ((unsigned int)u) << 16;
    return v.f;
}
__device__ __forceinline__ unsigned short f2bf(float f) {
    __hip_bfloat16 h = __float2bfloat16(f);
    return *reinterpret_cast<unsigned short*>(&h);
}
__device__ __forceinline__ void stc(unsigned short* C, size_t i, float v) { C[i] = f2bf(v); }
__device__ __forceinline__ void stc(float* C, size_t i, float v) { C[i] = v; }

// ---------------------------------------------------------------------------
// One-time fp32 -> bf16 conversion of x, y, Wq, Wk, Wv, Wo into workspace.
// ---------------------------------------------------------------------------
__global__ __launch_bounds__(256) void cvt_all(
    const float* __restrict__ x,  const float* __restrict__ y,
    const float* __restrict__ wq, const float* __restrict__ wk,
    const float* __restrict__ wv, const float* __restrict__ wo,
    unsigned short* __restrict__ xb,  unsigned short* __restrict__ yb,
    unsigned short* __restrict__ wqb, unsigned short* __restrict__ wkb,
    unsigned short* __restrict__ wvb, unsigned short* __restrict__ wob)
{
    const float* src; unsigned short* dst; int n4;
    switch (blockIdx.y) {
        case 0: src = x;  dst = xb;  n4 = (BATCH * LQ * DIM) / 4; break;
        case 1: src = y;  dst = yb;  n4 = (BATCH * LK * DIM) / 4; break;
        case 2: src = wq; dst = wqb; n4 = (INNER * DIM) / 4; break;
        case 3: src = wk; dst = wkb; n4 = (INNER * DIM) / 4; break;
        case 4: src = wv; dst = wvb; n4 = (INNER * DIM) / 4; break;
        default: src = wo; dst = wob; n4 = (INNER * DIM) / 4; break;
    }
    for (int i = blockIdx.x * 256 + threadIdx.x; i < n4; i += gridDim.x * 256) {
        float4 f = ((const float4*)src)[i];
        ushort4 u;
        u.x = f2bf(f.x); u.y = f2bf(f.y); u.z = f2bf(f.z); u.w = f2bf(f.w);
        ((ushort4*)dst)[i] = u;
    }
}

// ---------------------------------------------------------------------------
// Pack mask into bits: bit k of mbits[row][c] = (mask[row][c*64+k] > 0.5).
// ---------------------------------------------------------------------------
__global__ __launch_bounds__(256) void pack_mask(
    const float* __restrict__ mask, unsigned long long* __restrict__ mbits)
{
    const int row = blockIdx.x * 4 + (threadIdx.x >> 6);   // 4096 rows
    const int lane = threadIdx.x & 63;
    const float* mp = mask + (size_t)row * LK;
    unsigned long long* ob = mbits + (size_t)row * (LK / 64);
    for (int c = 0; c < LK / 64; ++c) {
        unsigned long long bal = __ballot(mp[c * 64 + lane] > 0.5f);
        if (lane == 0) ob[c] = bal;
    }
}

// ---------------------------------------------------------------------------
// C = scale * (A[M,K] @ W[N,K]^T), bf16 in, fp32 accum. 128x128 tile, BK=64,
// 4 waves. Double-buffered LDS + register prefetch: one barrier per K-tile.
// EPI=0: row-major C. EPI=1: V-transposed epilogue into vt[b][h][d][key],
// via per-wave LDS transpose (coalesced 128B-run stores).
// ---------------------------------------------------------------------------
#define LDT 72
#define TILE_US (128 * LDT)   // one LDS buffer in ushorts

template <typename TC, int EPI>
__device__ __forceinline__ void gemm_body(
    const unsigned short* __restrict__ A,
    const unsigned short* __restrict__ W,
    TC* __restrict__ C,
    int K, int N, float scale,
    unsigned short* As, unsigned short* Bs)   // each 2*TILE_US
{
    const int tid = threadIdx.x;
    const int m0 = blockIdx.x * 128;
    const int n0 = blockIdx.y * 128;
    const int w = tid >> 6, lane = tid & 63;
    const int q4 = lane >> 4, l16 = lane & 15;
    const int wm = (w >> 1) * 64, wn = (w & 1) * 64;

    int srow[4], sch[4];
#pragma unroll
    for (int i = 0; i < 4; ++i) { int c = tid + i * 256; srow[i] = c >> 3; sch[i] = c & 7; }

    f32x4 acc[4][4] = {};
    uint4 ar[4], br[4];

#pragma unroll
    for (int i = 0; i < 4; ++i) {
        ar[i] = *(const uint4*)(A + (size_t)(m0 + srow[i]) * K + sch[i] * 8);
        br[i] = *(const uint4*)(W + (size_t)(n0 + srow[i]) * K + sch[i] * 8);
    }
#pragma unroll
    for (int i = 0; i < 4; ++i) {
        *(uint4*)(As + srow[i] * LDT + sch[i] * 8) = ar[i];
        *(uint4*)(Bs + srow[i] * LDT + sch[i] * 8) = br[i];
    }
    __syncthreads();

    const int nt = K / 64;
    for (int t = 0; t < nt; ++t) {
        const int cur = (t & 1) * TILE_US;
        if (t + 1 < nt) {
            int kk = (t + 1) * 64;
#pragma unroll
            for (int i = 0; i < 4; ++i) {
                ar[i] = *(const uint4*)(A + (size_t)(m0 + srow[i]) * K + kk + sch[i] * 8);
                br[i] = *(const uint4*)(W + (size_t)(n0 + srow[i]) * K + kk + sch[i] * 8);
            }
        }

#pragma unroll
        for (int ks = 0; ks < 2; ++ks) {
            short8 a[4], b[4];
#pragma unroll
            for (int i = 0; i < 4; ++i)
                a[i] = *(const short8*)(As + cur + (wm + i * 16 + l16) * LDT + (ks * 4 + q4) * 8);
#pragma unroll
            for (int j = 0; j < 4; ++j)
                b[j] = *(const short8*)(Bs + cur + (wn + j * 16 + l16) * LDT + (ks * 4 + q4) * 8);
#pragma unroll
            for (int i = 0; i < 4; ++i)
#pragma unroll
                for (int j = 0; j < 4; ++j)
                    acc[i][j] = __builtin_amdgcn_mfma_f32_16x16x32_bf16(
                        a[i], b[j], acc[i][j], 0, 0, 0);
        }

        if (t + 1 < nt) {
            const int nxt = TILE_US - cur;
#pragma unroll
            for (int i = 0; i < 4; ++i) {
                *(uint4*)(As + nxt + srow[i] * LDT + sch[i] * 8) = ar[i];
                *(uint4*)(Bs + nxt + srow[i] * LDT + sch[i] * 8) = br[i];
            }
        }
        __syncthreads();
    }

    if (EPI == 0) {
        // C/D layout: col = lane&15, row = quad*4 + reg  [m89-verified]
#pragma unroll
        for (int i = 0; i < 4; ++i)
#pragma unroll
            for (int j = 0; j < 4; ++j)
#pragma unroll
                for (int r = 0; r < 4; ++r) {
                    int row = m0 + wm + i * 16 + q4 * 4 + r;
                    int col = n0 + wn + j * 16 + l16;
                    stc(C, (size_t)row * N + col, acc[i][j][r] * scale);
                }
    } else {
        // per-wave LDS transpose of the 64x64 quadrant, then coalesced stores.
        // As is free after the final barrier; regions are wave-private.
        unsigned short* TP = As + w * 4608;   // 64 d-rows x 72 (keys+pad)
#pragma unroll
        for (int i = 0; i < 4; ++i)
#pragma unroll
            for (int j = 0; j < 4; ++j) {
                ushort4 u;
                u.x = f2bf(acc[i][j][0]); u.y = f2bf(acc[i][j][1]);
                u.z = f2bf(acc[i][j][2]); u.w = f2bf(acc[i][j][3]);
                *(ushort4*)(TP + (j * 16 + l16) * 72 + i * 16 + q4 * 4) = u;
            }
        const int keyflat = m0 + wm;               // 64-aligned
        const int bb = keyflat >> 11, key0 = keyflat & (LK - 1);
        const int hh = (n0 + wn) >> 6;             // d base is 64-aligned
#pragma unroll
        for (int pass = 0; pass < 8; ++pass) {
            int dl = pass * 8 + (lane >> 3);
            int off = (lane & 7) * 8;
            uint4 v = *(const uint4*)(TP + dl * 72 + off);
            *(uint4*)((unsigned short*)C +
                ((size_t)((bb * HEADS + hh) * DH + dl)) * LK + key0 + off) = v;
        }
    }
}

__global__ __launch_bounds__(256) void proj_qkv(
    const unsigned short* __restrict__ xb, const unsigned short* __restrict__ yb,
    const unsigned short* __restrict__ wqb, const unsigned short* __restrict__ wkb,
    const unsigned short* __restrict__ wvb,
    unsigned short* __restrict__ qb, unsigned short* __restrict__ kb,
    unsigned short* __restrict__ vt)
{
    __shared__ __align__(16) unsigned short As[2 * TILE_US];
    __shared__ __align__(16) unsigned short Bs[2 * TILE_US];
    const int z = blockIdx.z;
    const unsigned short* A = (z == 0) ? xb : yb;
    const unsigned short* W = (z == 0) ? wqb : (z == 1) ? wkb : wvb;
    if (z == 2)
        gemm_body<unsigned short, 1>(A, W, vt, DIM, INNER, 1.0f, As, Bs);
    else
        gemm_body<unsigned short, 0>(A, W, (z == 0) ? qb : kb, DIM, INNER,
                                     (z == 0) ? 0.125f : 1.0f, As, Bs);
}

__global__ __launch_bounds__(256) void gemm_out(
    const unsigned short* __restrict__ A,
    const unsigned short* __restrict__ W,
    float* __restrict__ C)
{
    __shared__ __align__(16) unsigned short As[2 * TILE_US];
    __shared__ __align__(16) unsigned short Bs[2 * TILE_US];
    gemm_body<float, 0>(A, W, C, INNER, DIM, 1.0f, As, Bs);
}

// ---------------------------------------------------------------------------
// Flash attention, waves split KEYS (wave w owns keys [w*512, w*512+512) for
// ALL 64 q rows of the block). Wave-private LDS staging -> ZERO barriers in
// the main loop (per-wave DS ops are program-ordered). No-max softmax makes
// wave partials additive: one final barrier, sum o and l across waves.
// P overwrites the K region after S (same-wave in-order DS).
// ---------------------------------------------------------------------------
#define ALDT 72
#define AWRE (2 * 64 * ALDT)   // per-wave region: K/P buf + V buf = 9216 us

__global__ __launch_bounds__(256, 2) void attn_mfma(
    const unsigned short* __restrict__ Q,
    const unsigned short* __restrict__ Kb,
    const unsigned short* __restrict__ Vt,
    const unsigned long long* __restrict__ Mb,
    unsigned short* __restrict__ O)
{
    __shared__ __align__(16) unsigned short L[4][AWRE];
    __shared__ float lsh[4][64];

    const int tid = threadIdx.x;
    const int q0 = blockIdx.x * 64;
    const int h = blockIdx.y, b = blockIdx.z;
    const int w = tid >> 6, lane = tid & 63;
    const int q4 = lane >> 4, l16 = lane & 15;

    unsigned short* KP = L[w];               // 64 x 72: K tile, then P
    unsigned short* VS = L[w] + 64 * ALDT;   // 64 x 72: V^T tile

    // Q fragments for all 4 m-subtiles (64 q rows), 2 k-chunks each
    short8 qf[4][2];
#pragma unroll
    for (int i = 0; i < 4; ++i) {
        const unsigned short* qp =
            Q + (size_t)(b * LQ + q0 + i * 16 + l16) * INNER + h * DH + q4 * 8;
        qf[i][0] = *(const short8*)(qp);
        qf[i][1] = *(const short8*)(qp + 32);
    }

    f32x4 o[4][4] = {};          // [m-sub i][d-sub dd]
    float lacc[4][4] = {};       // [i][r]

    const unsigned short* kbase = Kb + (size_t)(b * LK) * INNER + h * DH;
    const unsigned short* vbase = Vt + (size_t)((b * HEADS + h) * DH) * LK;
    const unsigned long long* mw = Mb + (size_t)(b * LQ + q0) * (LK / 64) + w * 8;
    // bits for (local q row, tile t): mw[qrow*32 + t]

    const int srow = lane >> 3, sch = lane & 7;
    const int k00 = w * 512;

    for (int t = 0; t < 8; ++t) {
        const int k0 = k00 + t * 64;
        // ---- wave-private staging: K [key][d], V^T [d][key] ----
#pragma unroll
        for (int ii = 0; ii < 8; ++ii) {
            int row = ii * 8 + srow;
            *(uint4*)(KP + row * ALDT + sch * 8) =
                *(const uint4*)(kbase + (size_t)(k0 + row) * INNER + sch * 8);
            *(uint4*)(VS + row * ALDT + sch * 8) =
                *(const uint4*)(vbase + (size_t)row * LK + k0 + sch * 8);
        }

        // ---- S = Q K^T for all 4 m-subtiles; kf shared across i ----
        f32x4 p[4][4];
#pragma unroll
        for (int i = 0; i < 4; ++i)
#pragma unroll
            for (int j = 0; j < 4; ++j) p[i][j] = f32x4{0.f, 0.f, 0.f, 0.f};
#pragma unroll
        for (int ks = 0; ks < 2; ++ks)
#pragma unroll
            for (int j = 0; j < 4; ++j) {
                short8 kf = *(const short8*)(KP + (j * 16 + l16) * ALDT + ks * 32 + q4 * 8);
#pragma unroll
                for (int i = 0; i < 4; ++i)
                    p[i][j] = __builtin_amdgcn_mfma_f32_16x16x32_bf16(
                        qf[i][ks], kf, p[i][j], 0, 0, 0);
            }

        // ---- p = masked ? 0 : exp(s); per-lane l partials ----
#pragma unroll
        for (int i = 0; i < 4; ++i)
#pragma unroll
            for (int r = 0; r < 4; ++r) {
                unsigned long long bits = mw[(size_t)(i * 16 + q4 * 4 + r) * (LK / 64) + t];
#pragma unroll
                for (int j = 0; j < 4; ++j) {
                    float e = __expf(p[i][j][r]);
                    float pe = ((bits >> (j * 16 + l16)) & 1ull) ? 0.f : e;
                    p[i][j][r] = pe;
                    lacc[i][r] += pe;
                }
            }

        // ---- write P into KP (K reads all done; same-wave order) ----
#pragma unroll
        for (int i = 0; i < 4; ++i)
#pragma unroll
            for (int j = 0; j < 4; ++j)
#pragma unroll
                for (int r = 0; r < 4; ++r)
                    KP[(i * 16 + q4 * 4 + r) * ALDT + j * 16 + l16] = f2bf(p[i][j][r]);

        // ---- O += P V ; vf shared across i ----
#pragma unroll
        for (int ks = 0; ks < 2; ++ks) {
            short8 pf[4];
#pragma unroll
            for (int i = 0; i < 4; ++i)
                pf[i] = *(const short8*)(KP + (i * 16 + l16) * ALDT + ks * 32 + q4 * 8);
#pragma unroll
            for (int dd = 0; dd < 4; ++dd) {
                short8 vf = *(const short8*)(VS + (dd * 16 + l16) * ALDT + ks * 32 + q4 * 8);
#pragma unroll
                for (int i = 0; i < 4; ++i)
                    o[i][dd] = __builtin_amdgcn_mfma_f32_16x16x32_bf16(
                        pf[i], vf, o[i][dd], 0, 0, 0);
            }
        }
    }

    // ---- reduce l over the 16 key-lanes ----
#pragma unroll
    for (int off = 1; off < 16; off <<= 1)
#pragma unroll
        for (int i = 0; i < 4; ++i)
#pragma unroll
            for (int r = 0; r < 4; ++r)
                lacc[i][r] += __shfl_xor(lacc[i][r], off);

    // ---- dump per-wave o (fp32, row stride 65 words: 2-way max aliasing) ----
    float* ow = (float*)L[w];
#pragma unroll
    for (int i = 0; i < 4; ++i)
#pragma unroll
        for (int dd = 0; dd < 4; ++dd)
#pragma unroll
            for (int r = 0; r < 4; ++r)
                ow[(i * 16 + q4 * 4 + r) * 65 + dd * 16 + l16] = o[i][dd][r];
    if (l16 == 0)
#pragma unroll
        for (int i = 0; i < 4; ++i)
#pragma unroll
            for (int r = 0; r < 4; ++r)
                lsh[w][i * 16 + q4 * 4 + r] = lacc[i][r];
    __syncthreads();

    // ---- combine: wave w handles q rows [w*16, w*16+16); lane: q=w*16+l16 ----
    {
        const int q = w * 16 + l16;
        const float lt = lsh[0][q] + lsh[1][q] + lsh[2][q] + lsh[3][q];
        const float inv = 1.0f / lt;
        const float* o0 = (const float*)L[0];
        const float* o1 = (const float*)L[1];
        const float* o2 = (const float*)L[2];
        const float* o3 = (const float*)L[3];
        const int base = q * 65 + q4 * 16;
        unsigned short* op = O + (size_t)(b * LQ + q0 + q) * INNER + h * DH + q4 * 16;
#pragma unroll
        for (int c = 0; c < 4; ++c) {
            ushort4 u;
#pragma unroll
            for (int e = 0; e < 4; ++e) {
                int d = c * 4 + e;
                float s = o0[base + d] + o1[base + d] + o2[base + d] + o3[base + d];
                ((unsigned short*)&u)[e] = f2bf(s * inv);
            }
            *(ushort4*)(op + c * 4) = u;
        }
    }
}

extern "C" void kernel_launch(void* const* d_in, const int* in_sizes, int n_in,
                              void* d_out, int out_size, void* d_ws, size_t ws_size,
                              hipStream_t stream) {
    const float* x    = (const float*)d_in[0];
    const float* y    = (const float*)d_in[1];
    const float* mask = (const float*)d_in[2];
    const float* Wq   = (const float*)d_in[3];
    const float* Wk   = (const float*)d_in[4];
    const float* Wv   = (const float*)d_in[5];
    const float* Wo   = (const float*)d_in[6];
    float* out = (float*)d_out;

    const size_t NX = (size_t)BATCH * LQ * DIM;    // 4.19M
    const size_t NS = (size_t)BATCH * LQ * INNER;  // 2.10M
    const size_t NW = (size_t)INNER * DIM;         // 0.52M
    unsigned short* xb  = (unsigned short*)d_ws;
    unsigned short* yb  = xb + NX;
    unsigned short* qb  = yb + NX;
    unsigned short* kb  = qb + NS;
    unsigned short* vt  = kb + NS;
    unsigned short* wqb = vt + NS;
    unsigned short* wkb = wqb + NW;
    unsigned short* wvb = wkb + NW;
    unsigned short* wob = wvb + NW;
    unsigned long long* mbits = (unsigned long long*)(wob + NW);
    unsigned short* ao  = xb;   // xb dead after proj
    // ws: 2*NX + 3*NS + 4*NW bf16 (33.8MB) + 1MB bits = ~34.8 MB

    dim3 blk(256);
    cvt_all<<<dim3(160, 6), blk, 0, stream>>>(
        x, y, Wq, Wk, Wv, Wo, xb, yb, wqb, wkb, wvb, wob);
    pack_mask<<<dim3(BATCH * LQ / 4), blk, 0, stream>>>(mask, mbits);
    proj_qkv<<<dim3(4096 / 128, INNER / 128, 3), blk, 0, stream>>>(
        xb, yb, wqb, wkb, wvb, qb, kb, vt);
    attn_mfma<<<dim3(LQ / 64, HEADS, BATCH), blk, 0, stream>>>(
        qb, kb, vt, mbits, ao);
    gemm_out<<<dim3(4096 / 128, DIM / 128), blk, 0, stream>>>(ao, wob, out);
}